// Round 11
// baseline (194.247 us; speedup 1.0000x reference)
//
#include <hip/hip_runtime.h>
#include <math.h>

#define N_TOT 4194304      // 64*256*256
#define CONV_BLOCKS 512    // 8 co-groups (8 ch each) x 64 tiles (32x32)
#define XS_PAD 4864        // 19 slots x 256 threads (cells >=4624 junk)

__device__ __forceinline__ float sgnf(float x) {
    return x > 0.f ? 1.f : (x < 0.f ? -1.f : 0.f);
}

__device__ __forceinline__ float gelu_f(float v) {
    const float c0 = 0.7978845608028654f;
    float inner = c0 * fmaf(0.044715f * v, v * v, v);
    return 0.5f * v * (1.f + tanhf(inner));
}

// async HBM->LDS, 4 bytes/lane. LDS dest = wave-uniform base + lane*4;
// all lanes must stay active (exec mask shifts the readfirstlane'd base).
__device__ __forceinline__ void gll4(const float* g, float* l) {
    __builtin_amdgcn_global_load_lds((const __attribute__((address_space(1))) void*)g,
                                     (__attribute__((address_space(3))) void*)l, 4, 0, 0);
}

// ---------------------------------------------------------------------------
// Kernel A: per-channel Hopfield fixed-point -> alpha[c] = bp_c . v5
// sign(q*bp) factors: sign(W@(s*v)) = s*sign(W@v) for s=+-1, so the 5-iter
// recurrence is pixel-independent. y = q + sgn(q)*alpha[c].
// ---------------------------------------------------------------------------
__global__ __launch_bounds__(64) void alpha_kernel(const float* __restrict__ bp,
                                                   const float* __restrict__ Wm,
                                                   float* __restrict__ alpha) {
    const int c = blockIdx.x, d = threadIdx.x;
    __shared__ float v[64];
    float bpv = bp[c * 64 + d];
    v[d] = sgnf(bpv);
    __syncthreads();
    const float* row = Wm + c * 4096 + d * 64;
    for (int it = 0; it < 5; ++it) {
        float s = 0.f;
        #pragma unroll
        for (int e = 0; e < 64; ++e) s = fmaf(row[e], v[e], s);
        __syncthreads();
        v[d] = sgnf(s);
        __syncthreads();
    }
    float val = bpv * v[d];
    #pragma unroll
    for (int off = 32; off; off >>= 1) val += __shfl_down(val, off);
    if (d == 0) alpha[c] = val;
}

// ---------------------------------------------------------------------------
// Kernel B: 3x3 SAME conv (fp32) + bias + fused y = q + sgn(q)*alpha[c].
// Block: 256 thr, 32x32 pixel tile, EIGHT output channels.
// Thread: 2x2-STRIDED micro-tile (rows 2ty,2ty+1; cols tx,tx+16) x 8 co.
//   Tap pattern identical to R8 (row stride 136; measured 0 conflicts);
//   24 taps/ci now feed 288 FMAs (1:12) -> LDS-pipe time halves vs R8.
// Weights: direct wave-uniform cw reads (R8-proven s_load path).
// Staging: global_load_lds double-buffer, 19 full unmasked slots; OOB lanes
//   pull a 256B zero page so halo cells get exact zeros each slab.
// Grid: cog(8) x tile(64); same-tile blocks differ by 64 -> same XCD.
// ---------------------------------------------------------------------------
__global__ __launch_bounds__(256, 2) void conv_kernel(const float* __restrict__ x,
                                                      const float* __restrict__ cw,
                                                      const float* __restrict__ cb,
                                                      const float* __restrict__ alpha,
                                                      const float* __restrict__ zbuf,
                                                      float* __restrict__ y,
                                                      double* __restrict__ partials) {
    const int tid = threadIdx.x;
    const int b = blockIdx.x;
    const int tile = b & 63;
    const int cog = b >> 6;                   // 8 output channels per group
    const int bx = tile & 7, by = tile >> 3;  // 8x8 tiles of 32x32
    const int tx = tid & 15, ty = tid >> 4;   // cols tx,tx+16; rows 2ty,2ty+1

    __shared__ float xs[2][XS_PAD];           // [buf][r*136 + ci*34 + c]
    __shared__ double red[4][2];

    // ---- staging descriptors (19 full slots), computed once ----
    int voff[19];
    unsigned vmask = 0u;
    #pragma unroll
    for (int i = 0; i < 19; ++i) {
        int idx = i * 256 + tid;
        int r = idx / 136;
        int rem = idx - r * 136;
        int ci = rem / 34;
        int c = rem - ci * 34;
        int gy = (by << 5) - 1 + r;
        int gx = (bx << 5) + c - 1;
        bool ok = (idx < 4624) && ((unsigned)gy < 256u) && ((unsigned)gx < 256u);
        voff[i] = (ci << 16) + (gy << 8) + gx;
        if (ok) vmask |= (1u << i);
    }

    float acc[8][2][2];                       // [co][dy][colgroup]
    #pragma unroll
    for (int co = 0; co < 8; ++co) {
        float bias = cb[cog * 8 + co];
        acc[co][0][0] = bias; acc[co][0][1] = bias;
        acc[co][1][0] = bias; acc[co][1][1] = bias;
    }

    // prologue: stage slab 0 into buf 0 (all lanes; OOB lanes pull zeros)
    #pragma unroll
    for (int i = 0; i < 19; ++i) {
        const float* src = (vmask & (1u << i)) ? (x + voff[i]) : zbuf;
        gll4(src, &xs[0][i * 256 + tid]);
    }
    __syncthreads();                          // vmcnt drain -> slab 0 ready

    const int lrow = (2 * ty) * 136 + tx;
    const float* wbase = cw + cog * 8 * 576;

    for (int s = 0; s < 16; ++s) {
        const int cur = s & 1;
        // prefetch slab s+1 into the other buffer (overlaps compute below)
        if (s < 15) {
            const float* xb = x + ((s + 1) << 18);   // +4 input channels
            #pragma unroll
            for (int i = 0; i < 19; ++i) {
                const float* src = (vmask & (1u << i)) ? (xb + voff[i]) : zbuf;
                gll4(src, &xs[cur ^ 1][i * 256 + tid]);
            }
        }

        const float* xsc = xs[cur];
        #pragma unroll
        for (int ci = 0; ci < 4; ++ci) {
            float t[4][6];                    // 4 window rows x (3+3) taps
            #pragma unroll
            for (int rr = 0; rr < 4; ++rr) {
                const int off = lrow + rr * 136 + ci * 34;
                t[rr][0] = xsc[off];      t[rr][1] = xsc[off + 1];  t[rr][2] = xsc[off + 2];
                t[rr][3] = xsc[off + 16]; t[rr][4] = xsc[off + 17]; t[rr][5] = xsc[off + 18];
            }
            const float* wp = wbase + (s * 4 + ci) * 9;
            #pragma unroll
            for (int co = 0; co < 8; ++co) {
                const float* w = wp + co * 576;     // wave-uniform -> s_load
                #pragma unroll
                for (int ky = 0; ky < 3; ++ky)
                    #pragma unroll
                    for (int kx = 0; kx < 3; ++kx) {
                        float wv = w[ky * 3 + kx];
                        #pragma unroll
                        for (int dy = 0; dy < 2; ++dy)
                            #pragma unroll
                            for (int g = 0; g < 2; ++g)
                                acc[co][dy][g] = fmaf(wv, t[dy + ky][g * 3 + kx], acc[co][dy][g]);
                    }
            }
        }
        __syncthreads();   // compute-s reads done + prefetch s+1 landed
    }

    // epilogue: y = q + sgn(q)*alpha, stores + f64 partial sums
    double s1 = 0.0, s2 = 0.0;
    const int gx0 = (bx << 5) + tx;
    const int gy0 = (by << 5) + 2 * ty;
    #pragma unroll
    for (int co = 0; co < 8; ++co) {
        float a = alpha[cog * 8 + co];
        const int cb_off = (cog * 8 + co) << 16;
        #pragma unroll
        for (int dy = 0; dy < 2; ++dy) {
            #pragma unroll
            for (int g = 0; g < 2; ++g) {
                float q = acc[co][dy][g];
                float yv = q + (q > 0.f ? a : (q < 0.f ? -a : 0.f));
                y[cb_off + ((gy0 + dy) << 8) + gx0 + g * 16] = yv;
                s1 += (double)yv;
                s2 += (double)yv * (double)yv;
            }
        }
    }
    #pragma unroll
    for (int off = 32; off; off >>= 1) {
        s1 += __shfl_down(s1, off);
        s2 += __shfl_down(s2, off);
    }
    const int wid = tid >> 6;
    if ((tid & 63) == 0) { red[wid][0] = s1; red[wid][1] = s2; }
    __syncthreads();
    if (tid == 0) {
        double a1 = red[0][0] + red[1][0] + red[2][0] + red[3][0];
        double a2 = red[0][1] + red[1][1] + red[2][1] + red[3][1];
        partials[b * 2]     = a1;
        partials[b * 2 + 1] = a2;
    }
}

// ---------------------------------------------------------------------------
// Kernel C: reduce CONV_BLOCKS partial pairs -> mean, inv_std (deterministic)
// ---------------------------------------------------------------------------
__global__ __launch_bounds__(256) void stats_kernel(const double* __restrict__ partials,
                                                    float* __restrict__ stats) {
    const int tid = threadIdx.x;
    double s1 = 0.0, s2 = 0.0;
    for (int i = tid; i < CONV_BLOCKS; i += 256) {
        s1 += partials[2 * i];
        s2 += partials[2 * i + 1];
    }
    #pragma unroll
    for (int off = 32; off; off >>= 1) {
        s1 += __shfl_down(s1, off);
        s2 += __shfl_down(s2, off);
    }
    __shared__ double red[4][2];
    const int wid = tid >> 6;
    if ((tid & 63) == 0) { red[wid][0] = s1; red[wid][1] = s2; }
    __syncthreads();
    if (tid == 0) {
        double a1 = red[0][0] + red[1][0] + red[2][0] + red[3][0];
        double a2 = red[0][1] + red[1][1] + red[2][1] + red[3][1];
        double mean = a1 / (double)N_TOT;
        double var = a2 / (double)N_TOT - mean * mean;
        stats[0] = (float)mean;
        stats[1] = (float)(1.0 / sqrt(var + 1e-5));
    }
}

// ---------------------------------------------------------------------------
// Kernel D: in-place norm-affine + gelu, float4 vectorized
// ---------------------------------------------------------------------------
__global__ __launch_bounds__(256) void finalize_kernel(float* __restrict__ y,
                                                       const float* __restrict__ stats,
                                                       const float* __restrict__ gnw,
                                                       const float* __restrict__ gnb) {
    const int i = blockIdx.x * 256 + threadIdx.x;  // float4 index
    const float mean = stats[0], istd = stats[1];
    const int c = i >> 14;
    const float scale = gnw[c] * istd;
    const float shift = gnb[c] - mean * scale;
    float4 v = reinterpret_cast<float4*>(y)[i];
    v.x = gelu_f(fmaf(v.x, scale, shift));
    v.y = gelu_f(fmaf(v.y, scale, shift));
    v.z = gelu_f(fmaf(v.z, scale, shift));
    v.w = gelu_f(fmaf(v.w, scale, shift));
    reinterpret_cast<float4*>(y)[i] = v;
}

extern "C" void kernel_launch(void* const* d_in, const int* in_sizes, int n_in,
                              void* d_out, int out_size, void* d_ws, size_t ws_size,
                              hipStream_t stream) {
    const float* x   = (const float*)d_in[0];
    const float* cw  = (const float*)d_in[1];
    const float* cb  = (const float*)d_in[2];
    const float* bp  = (const float*)d_in[3];
    const float* Wm  = (const float*)d_in[4];
    const float* gnw = (const float*)d_in[5];
    const float* gnb = (const float*)d_in[6];
    float* out = (float*)d_out;

    char* ws = (char*)d_ws;
    float* alpha     = (float*)ws;            // 64 floats
    float* stats     = (float*)(ws + 256);    // 2 floats
    double* partials = (double*)(ws + 512);   // CONV_BLOCKS*2 doubles
    float* zbuf      = (float*)(ws + 32768);  // 256B zero page for OOB lanes

    hipMemsetAsync(zbuf, 0, 256, stream);
    alpha_kernel<<<64, 64, 0, stream>>>(bp, Wm, alpha);
    conv_kernel<<<CONV_BLOCKS, 256, 0, stream>>>(x, cw, cb, alpha, zbuf, out, partials);
    stats_kernel<<<1, 256, 0, stream>>>(partials, stats);
    finalize_kernel<<<4096, 256, 0, stream>>>(out, stats, gnw, gnb);
}

// Round 12
// 102.121 us; speedup vs baseline: 1.9021x; 1.9021x over previous
//
#include <hip/hip_runtime.h>
#include <math.h>

#define N_TOT 4194304      // 64*256*256
#define CONV_BLOCKS 1024   // 16 co-groups x 64 tiles (32x32)
#define XS_PAD 4864        // 19 slots x 256 threads (cells >=4624 junk)

__device__ __forceinline__ float sgnf(float x) {
    return x > 0.f ? 1.f : (x < 0.f ? -1.f : 0.f);
}

__device__ __forceinline__ float gelu_f(float v) {
    const float c0 = 0.7978845608028654f;
    float inner = c0 * fmaf(0.044715f * v, v * v, v);
    return 0.5f * v * (1.f + tanhf(inner));
}

// async HBM->LDS, 4 bytes/lane. LDS dest = wave-uniform base + lane*4;
// all lanes must stay active (exec mask shifts the readfirstlane'd base).
__device__ __forceinline__ void gll4(const float* g, float* l) {
    __builtin_amdgcn_global_load_lds((const __attribute__((address_space(1))) void*)g,
                                     (__attribute__((address_space(3))) void*)l, 4, 0, 0);
}

// ---------------------------------------------------------------------------
// Kernel A: per-channel Hopfield fixed-point -> alpha[c] = bp_c . v5
// sign(q*bp) factors: sign(W@(s*v)) = s*sign(W@v) for s=+-1, so the 5-iter
// recurrence is pixel-independent. y = q + sgn(q)*alpha[c].
// ---------------------------------------------------------------------------
__global__ __launch_bounds__(64) void alpha_kernel(const float* __restrict__ bp,
                                                   const float* __restrict__ Wm,
                                                   float* __restrict__ alpha) {
    const int c = blockIdx.x, d = threadIdx.x;
    __shared__ float v[64];
    float bpv = bp[c * 64 + d];
    v[d] = sgnf(bpv);
    __syncthreads();
    const float* row = Wm + c * 4096 + d * 64;
    for (int it = 0; it < 5; ++it) {
        float s = 0.f;
        #pragma unroll
        for (int e = 0; e < 64; ++e) s = fmaf(row[e], v[e], s);
        __syncthreads();
        v[d] = sgnf(s);
        __syncthreads();
    }
    float val = bpv * v[d];
    #pragma unroll
    for (int off = 32; off; off >>= 1) val += __shfl_down(val, off);
    if (d == 0) alpha[c] = val;
}

// ---------------------------------------------------------------------------
// Kernel B: 3x3 SAME conv (fp32) + bias + fused y = q + sgn(q)*alpha[c].
// Block: 256 thr, 32x32 pixel tile, 4 output channels.
// Thread: 2x2 PAIRED micro-tile (rows 2ty,2ty+1; cols 2tx,2tx+1) x 4 co.
//   Window = stored cols 2tx..2tx+3 (base even) -> 2 aligned ds_read_b64
//   per window row, 8 b64/ci (was 24 b32/ci in R8 = 3x fewer LDS instrs).
//   Banks: dword base = 136*(2ty+rr) + 34ci + 2tx == even; a 16-lane phase
//   covers all 32 banks exactly once (<=1 access/bank/phase; R8's proven-
//   zero pattern had 2). Row step 136 == 8 mod 32 preserves coverage.
// Weights: direct wave-uniform cw reads (R8-proven s_load path).
// Staging: global_load_lds double-buffer, 19 full unmasked slots; OOB lanes
//   pull a 256B zero page so halo cells get exact zeros each slab.
// Grid: cog(16) x tile(64); same-tile blocks differ by 64 -> same XCD.
// ---------------------------------------------------------------------------
__global__ __launch_bounds__(256, 4) void conv_kernel(const float* __restrict__ x,
                                                      const float* __restrict__ cw,
                                                      const float* __restrict__ cb,
                                                      const float* __restrict__ alpha,
                                                      const float* __restrict__ zbuf,
                                                      float* __restrict__ y,
                                                      double* __restrict__ partials) {
    const int tid = threadIdx.x;
    const int b = blockIdx.x;
    const int tile = b & 63;
    const int cog = b >> 6;                   // 4 output channels per group
    const int bx = tile & 7, by = tile >> 3;  // 8x8 tiles of 32x32
    const int tx = tid & 15, ty = tid >> 4;   // cols 2tx,2tx+1; rows 2ty,2ty+1

    __shared__ float xs[2][XS_PAD];           // [buf][r*136 + ci*34 + c]
    __shared__ double red[4][2];

    // ---- staging descriptors (19 full slots), computed once ----
    int voff[19];
    unsigned vmask = 0u;
    #pragma unroll
    for (int i = 0; i < 19; ++i) {
        int idx = i * 256 + tid;
        int r = idx / 136;
        int rem = idx - r * 136;
        int ci = rem / 34;
        int c = rem - ci * 34;
        int gy = (by << 5) - 1 + r;
        int gx = (bx << 5) + c - 1;
        bool ok = (idx < 4624) && ((unsigned)gy < 256u) && ((unsigned)gx < 256u);
        voff[i] = (ci << 16) + (gy << 8) + gx;
        if (ok) vmask |= (1u << i);
    }

    float acc[4][2][2];                       // [co][dy][col j]
    #pragma unroll
    for (int co = 0; co < 4; ++co) {
        float bias = cb[cog * 4 + co];
        acc[co][0][0] = bias; acc[co][0][1] = bias;
        acc[co][1][0] = bias; acc[co][1][1] = bias;
    }

    // prologue: stage slab 0 into buf 0 (all lanes; OOB lanes pull zeros)
    #pragma unroll
    for (int i = 0; i < 19; ++i) {
        const float* src = (vmask & (1u << i)) ? (x + voff[i]) : zbuf;
        gll4(src, &xs[0][i * 256 + tid]);
    }
    __syncthreads();                          // vmcnt drain -> slab 0 ready

    const int lrow = (2 * ty) * 136 + 2 * tx; // even dword -> 8B aligned
    const float* wbase = cw + cog * 4 * 576;

    for (int s = 0; s < 16; ++s) {
        const int cur = s & 1;
        // prefetch slab s+1 into the other buffer (overlaps compute below)
        if (s < 15) {
            const float* xb = x + ((s + 1) << 18);   // +4 input channels
            #pragma unroll
            for (int i = 0; i < 19; ++i) {
                const float* src = (vmask & (1u << i)) ? (xb + voff[i]) : zbuf;
                gll4(src, &xs[cur ^ 1][i * 256 + tid]);
            }
        }

        const float* xsc = xs[cur];
        #pragma unroll
        for (int ci = 0; ci < 4; ++ci) {
            float t[4][4];                    // 4 window rows x 4 cols
            #pragma unroll
            for (int rr = 0; rr < 4; ++rr) {
                const int off = lrow + rr * 136 + ci * 34;   // even
                float2 a = *reinterpret_cast<const float2*>(&xsc[off]);
                float2 bb = *reinterpret_cast<const float2*>(&xsc[off + 2]);
                t[rr][0] = a.x; t[rr][1] = a.y; t[rr][2] = bb.x; t[rr][3] = bb.y;
            }
            const float* wp = wbase + (s * 4 + ci) * 9;
            #pragma unroll
            for (int co = 0; co < 4; ++co) {
                const float* w = wp + co * 576;     // wave-uniform -> s_load
                #pragma unroll
                for (int ky = 0; ky < 3; ++ky)
                    #pragma unroll
                    for (int kx = 0; kx < 3; ++kx) {
                        float wv = w[ky * 3 + kx];
                        #pragma unroll
                        for (int dy = 0; dy < 2; ++dy)
                            #pragma unroll
                            for (int j = 0; j < 2; ++j)
                                acc[co][dy][j] = fmaf(wv, t[dy + ky][kx + j], acc[co][dy][j]);
                    }
            }
        }
        __syncthreads();   // compute-s reads done + prefetch s+1 landed
    }

    // epilogue: y = q + sgn(q)*alpha, aligned float2 stores + f64 sums
    double s1 = 0.0, s2 = 0.0;
    const int gx0 = (bx << 5) + 2 * tx;
    const int gy0 = (by << 5) + 2 * ty;
    #pragma unroll
    for (int co = 0; co < 4; ++co) {
        float a = alpha[cog * 4 + co];
        const int cb_off = (cog * 4 + co) << 16;
        #pragma unroll
        for (int dy = 0; dy < 2; ++dy) {
            float q0 = acc[co][dy][0];
            float q1 = acc[co][dy][1];
            float y0v = q0 + (q0 > 0.f ? a : (q0 < 0.f ? -a : 0.f));
            float y1v = q1 + (q1 > 0.f ? a : (q1 < 0.f ? -a : 0.f));
            float2 pk; pk.x = y0v; pk.y = y1v;
            *reinterpret_cast<float2*>(&y[cb_off + ((gy0 + dy) << 8) + gx0]) = pk;
            s1 += (double)y0v + (double)y1v;
            s2 += (double)y0v * (double)y0v + (double)y1v * (double)y1v;
        }
    }
    #pragma unroll
    for (int off = 32; off; off >>= 1) {
        s1 += __shfl_down(s1, off);
        s2 += __shfl_down(s2, off);
    }
    const int wid = tid >> 6;
    if ((tid & 63) == 0) { red[wid][0] = s1; red[wid][1] = s2; }
    __syncthreads();
    if (tid == 0) {
        double a1 = red[0][0] + red[1][0] + red[2][0] + red[3][0];
        double a2 = red[0][1] + red[1][1] + red[2][1] + red[3][1];
        partials[b * 2]     = a1;
        partials[b * 2 + 1] = a2;
    }
}

// ---------------------------------------------------------------------------
// Kernel C: reduce CONV_BLOCKS partial pairs -> mean, inv_std (deterministic)
// ---------------------------------------------------------------------------
__global__ __launch_bounds__(256) void stats_kernel(const double* __restrict__ partials,
                                                    float* __restrict__ stats) {
    const int tid = threadIdx.x;
    double s1 = 0.0, s2 = 0.0;
    for (int i = tid; i < CONV_BLOCKS; i += 256) {
        s1 += partials[2 * i];
        s2 += partials[2 * i + 1];
    }
    #pragma unroll
    for (int off = 32; off; off >>= 1) {
        s1 += __shfl_down(s1, off);
        s2 += __shfl_down(s2, off);
    }
    __shared__ double red[4][2];
    const int wid = tid >> 6;
    if ((tid & 63) == 0) { red[wid][0] = s1; red[wid][1] = s2; }
    __syncthreads();
    if (tid == 0) {
        double a1 = red[0][0] + red[1][0] + red[2][0] + red[3][0];
        double a2 = red[0][1] + red[1][1] + red[2][1] + red[3][1];
        double mean = a1 / (double)N_TOT;
        double var = a2 / (double)N_TOT - mean * mean;
        stats[0] = (float)mean;
        stats[1] = (float)(1.0 / sqrt(var + 1e-5));
    }
}

// ---------------------------------------------------------------------------
// Kernel D: in-place norm-affine + gelu, float4 vectorized
// ---------------------------------------------------------------------------
__global__ __launch_bounds__(256) void finalize_kernel(float* __restrict__ y,
                                                       const float* __restrict__ stats,
                                                       const float* __restrict__ gnw,
                                                       const float* __restrict__ gnb) {
    const int i = blockIdx.x * 256 + threadIdx.x;  // float4 index
    const float mean = stats[0], istd = stats[1];
    const int c = i >> 14;
    const float scale = gnw[c] * istd;
    const float shift = gnb[c] - mean * scale;
    float4 v = reinterpret_cast<float4*>(y)[i];
    v.x = gelu_f(fmaf(v.x, scale, shift));
    v.y = gelu_f(fmaf(v.y, scale, shift));
    v.z = gelu_f(fmaf(v.z, scale, shift));
    v.w = gelu_f(fmaf(v.w, scale, shift));
    reinterpret_cast<float4*>(y)[i] = v;
}

extern "C" void kernel_launch(void* const* d_in, const int* in_sizes, int n_in,
                              void* d_out, int out_size, void* d_ws, size_t ws_size,
                              hipStream_t stream) {
    const float* x   = (const float*)d_in[0];
    const float* cw  = (const float*)d_in[1];
    const float* cb  = (const float*)d_in[2];
    const float* bp  = (const float*)d_in[3];
    const float* Wm  = (const float*)d_in[4];
    const float* gnw = (const float*)d_in[5];
    const float* gnb = (const float*)d_in[6];
    float* out = (float*)d_out;

    char* ws = (char*)d_ws;
    float* alpha     = (float*)ws;            // 64 floats
    float* stats     = (float*)(ws + 256);    // 2 floats
    double* partials = (double*)(ws + 512);   // CONV_BLOCKS*2 doubles
    float* zbuf      = (float*)(ws + 32768);  // 256B zero page for OOB lanes

    hipMemsetAsync(zbuf, 0, 256, stream);
    alpha_kernel<<<64, 64, 0, stream>>>(bp, Wm, alpha);
    conv_kernel<<<CONV_BLOCKS, 256, 0, stream>>>(x, cw, cb, alpha, zbuf, out, partials);
    stats_kernel<<<1, 256, 0, stream>>>(partials, stats);
    finalize_kernel<<<4096, 256, 0, stream>>>(out, stats, gnw, gnb);
}